// Round 2
// baseline (40.033 us; speedup 1.0000x reference)
//
#include <hip/hip_runtime.h>

#define HIDDEN  128
#define N_NODES 100000
#define N_EDGES 2000000

// Kernel 1: per-node dot products.
// 32 lanes per node; each lane handles 4 of the 128 floats (float4 = 16B,
// 32 lanes x 16B = 512B contiguous per row -> coalesced).
__global__ __launch_bounds__(256) void node_dots_kernel(
    const float* __restrict__ x_src,
    const float* __restrict__ x_dst,
    const float* __restrict__ w,    // [256]: first 128 = w_src, next 128 = w_dst
    float* __restrict__ s_tab,      // [N_NODES]
    float* __restrict__ d_tab)      // [N_NODES]
{
    int gid  = blockIdx.x * 256 + threadIdx.x;
    int node = gid >> 5;
    int lane = gid & 31;
    if (node >= N_NODES) return;

    const float4 ws = *reinterpret_cast<const float4*>(w + lane * 4);
    const float4 wd = *reinterpret_cast<const float4*>(w + HIDDEN + lane * 4);
    const float4 xs = *reinterpret_cast<const float4*>(x_src + (size_t)node * HIDDEN + lane * 4);
    const float4 xd = *reinterpret_cast<const float4*>(x_dst + (size_t)node * HIDDEN + lane * 4);

    float ss = xs.x * ws.x + xs.y * ws.y + xs.z * ws.z + xs.w * ws.w;
    float dd = xd.x * wd.x + xd.y * wd.y + xd.z * wd.z + xd.w * wd.w;

    // Reduce across the 32-lane group (offsets < 32 keep it within the group).
    #pragma unroll
    for (int off = 16; off; off >>= 1) {
        ss += __shfl_xor(ss, off);
        dd += __shfl_xor(dd, off);
    }
    if (lane == 0) {
        s_tab[node] = ss;
        d_tab[node] = dd;
    }
}

// Kernel 2: per-edge gather + add. 4 edges per thread (int4 index loads,
// float4 stores). s/d tables are 400KB each -> L2 resident.
__global__ __launch_bounds__(256) void edge_kernel(
    const int* __restrict__ idx,          // [2 * N_EDGES], row0 = src, row1 = dst
    const float* __restrict__ s_tab,
    const float* __restrict__ d_tab,
    const float* __restrict__ bias,       // [1]
    float* __restrict__ out)              // [N_EDGES]
{
    int t = blockIdx.x * 256 + threadIdx.x;
    if (t >= N_EDGES / 4) return;

    const int4 a = reinterpret_cast<const int4*>(idx)[t];
    const int4 b = reinterpret_cast<const int4*>(idx + N_EDGES)[t];
    const float bv = bias[0];

    float4 o;
    o.x = s_tab[a.x] + d_tab[b.x] + bv;
    o.y = s_tab[a.y] + d_tab[b.y] + bv;
    o.z = s_tab[a.z] + d_tab[b.z] + bv;
    o.w = s_tab[a.w] + d_tab[b.w] + bv;

    reinterpret_cast<float4*>(out)[t] = o;
}

extern "C" void kernel_launch(void* const* d_in, const int* in_sizes, int n_in,
                              void* d_out, int out_size, void* d_ws, size_t ws_size,
                              hipStream_t stream) {
    const float* x_src = (const float*)d_in[0];
    const float* x_dst = (const float*)d_in[1];
    const int*   idx   = (const int*)d_in[2];
    const float* w     = (const float*)d_in[3];
    const float* bias  = (const float*)d_in[4];
    float* out = (float*)d_out;

    float* s_tab = (float*)d_ws;
    float* d_tab = s_tab + N_NODES;

    // Kernel 1: 32 threads per node.
    {
        int total_threads = N_NODES * 32;
        int blocks = (total_threads + 255) / 256;
        node_dots_kernel<<<blocks, 256, 0, stream>>>(x_src, x_dst, w, s_tab, d_tab);
    }
    // Kernel 2: 4 edges per thread.
    {
        int threads = N_EDGES / 4;
        int blocks = (threads + 255) / 256;
        edge_kernel<<<blocks, 256, 0, stream>>>(idx, s_tab, d_tab, bias, out);
    }
}

// Round 4
// 39.631 us; speedup vs baseline: 1.0101x; 1.0101x over previous
//
#include <hip/hip_runtime.h>

#define HIDDEN  128
#define N_NODES 100000
#define N_EDGES 2000000

typedef float f32x4 __attribute__((ext_vector_type(4)));
typedef int   i32x4 __attribute__((ext_vector_type(4)));

// Kernel 1: per-node dot products.
// 16 lanes per node; each lane loads 2 x float4 from each row (8 floats),
// giving 4 x 16B loads in flight per thread. 16-lane shuffle reduction.
__global__ __launch_bounds__(256) void node_dots_kernel(
    const float* __restrict__ x_src,
    const float* __restrict__ x_dst,
    const float* __restrict__ w,    // [256]: first 128 = w_src, next 128 = w_dst
    float* __restrict__ s_tab,      // [N_NODES]
    float* __restrict__ d_tab)      // [N_NODES]
{
    int gid  = blockIdx.x * 256 + threadIdx.x;
    int node = gid >> 4;
    int lane = gid & 15;
    if (node >= N_NODES) return;

    const f32x4* wv = reinterpret_cast<const f32x4*>(w);
    const f32x4 ws0 = wv[lane];           // w[4l .. 4l+3]
    const f32x4 ws1 = wv[lane + 16];      // w[64+4l ..]
    const f32x4 wd0 = wv[lane + 32];      // w[128+4l ..]
    const f32x4 wd1 = wv[lane + 48];      // w[192+4l ..]

    const f32x4* xs = reinterpret_cast<const f32x4*>(x_src + (size_t)node * HIDDEN);
    const f32x4* xd = reinterpret_cast<const f32x4*>(x_dst + (size_t)node * HIDDEN);
    const f32x4 a0 = __builtin_nontemporal_load(xs + lane);
    const f32x4 a1 = __builtin_nontemporal_load(xs + lane + 16);
    const f32x4 b0 = __builtin_nontemporal_load(xd + lane);
    const f32x4 b1 = __builtin_nontemporal_load(xd + lane + 16);

    float ss = a0.x*ws0.x + a0.y*ws0.y + a0.z*ws0.z + a0.w*ws0.w
             + a1.x*ws1.x + a1.y*ws1.y + a1.z*ws1.z + a1.w*ws1.w;
    float dd = b0.x*wd0.x + b0.y*wd0.y + b0.z*wd0.z + b0.w*wd0.w
             + b1.x*wd1.x + b1.y*wd1.y + b1.z*wd1.z + b1.w*wd1.w;

    // Reduce across the 16-lane group.
    #pragma unroll
    for (int off = 8; off; off >>= 1) {
        ss += __shfl_xor(ss, off);
        dd += __shfl_xor(dd, off);
    }
    if (lane == 0) {
        s_tab[node] = ss;
        d_tab[node] = dd;
    }
}

// Kernel 2: per-edge gather + add. 8 edges per thread (2x int4 per index row,
// 2x float4 stores). s/d tables are 400KB each -> L2 resident; streaming
// traffic (idx, out) is nontemporal so it doesn't evict them.
__global__ __launch_bounds__(256) void edge_kernel(
    const int* __restrict__ idx,          // [2 * N_EDGES], row0 = src, row1 = dst
    const float* __restrict__ s_tab,
    const float* __restrict__ d_tab,
    const float* __restrict__ bias,       // [1]
    float* __restrict__ out)              // [N_EDGES]
{
    int t = blockIdx.x * 256 + threadIdx.x;
    if (t >= N_EDGES / 8) return;

    const i32x4* ia = reinterpret_cast<const i32x4*>(idx);
    const i32x4* ib = reinterpret_cast<const i32x4*>(idx + N_EDGES);
    const i32x4 a0 = __builtin_nontemporal_load(ia + 2 * t);
    const i32x4 a1 = __builtin_nontemporal_load(ia + 2 * t + 1);
    const i32x4 b0 = __builtin_nontemporal_load(ib + 2 * t);
    const i32x4 b1 = __builtin_nontemporal_load(ib + 2 * t + 1);
    const float bv = bias[0];

    f32x4 o0, o1;
    o0.x = s_tab[a0.x] + d_tab[b0.x] + bv;
    o0.y = s_tab[a0.y] + d_tab[b0.y] + bv;
    o0.z = s_tab[a0.z] + d_tab[b0.z] + bv;
    o0.w = s_tab[a0.w] + d_tab[b0.w] + bv;
    o1.x = s_tab[a1.x] + d_tab[b1.x] + bv;
    o1.y = s_tab[a1.y] + d_tab[b1.y] + bv;
    o1.z = s_tab[a1.z] + d_tab[b1.z] + bv;
    o1.w = s_tab[a1.w] + d_tab[b1.w] + bv;

    f32x4* ov = reinterpret_cast<f32x4*>(out);
    __builtin_nontemporal_store(o0, ov + 2 * t);
    __builtin_nontemporal_store(o1, ov + 2 * t + 1);
}

extern "C" void kernel_launch(void* const* d_in, const int* in_sizes, int n_in,
                              void* d_out, int out_size, void* d_ws, size_t ws_size,
                              hipStream_t stream) {
    const float* x_src = (const float*)d_in[0];
    const float* x_dst = (const float*)d_in[1];
    const int*   idx   = (const int*)d_in[2];
    const float* w     = (const float*)d_in[3];
    const float* bias  = (const float*)d_in[4];
    float* out = (float*)d_out;

    float* s_tab = (float*)d_ws;
    float* d_tab = s_tab + N_NODES;

    // Kernel 1: 16 threads per node.
    {
        int total_threads = N_NODES * 16;              // 1.6M
        int blocks = (total_threads + 255) / 256;      // 6250
        node_dots_kernel<<<blocks, 256, 0, stream>>>(x_src, x_dst, w, s_tab, d_tab);
    }
    // Kernel 2: 8 edges per thread.
    {
        int threads = N_EDGES / 8;                     // 250000
        int blocks = (threads + 255) / 256;            // 977
        edge_kernel<<<blocks, 256, 0, stream>>>(idx, s_tab, d_tab, bias, out);
    }
}